// Round 9
// baseline (75.102 us; speedup 1.0000x reference)
//
#include <hip/hip_runtime.h>

// Problem constants (match reference)
#define S_AR 3072
#define NH 16
#define NB 4
#define ND 128
#define NTOT (S_AR * NH * NB * ND)   // 25,165,824 elems per tensor
#define N4   (NTOT / 4)              // 6,291,456 float4 per tensor
#define TPB 256
#define HALF_BLOCKS 1024             // blocks per tensor (2048 total = 8/CU, all-resident)
#define STRIDE (HALF_BLOCKS * TPB)   // 262,144 threads per tensor (2^18)
#define ITERS (N4 / STRIDE)          // exactly 24, no remainder

// Native clang vector type — required by __builtin_nontemporal_{load,store}
typedef float vf4 __attribute__((ext_vector_type(4)));

__device__ __forceinline__ float max4abs(vf4 a) {
    return fmaxf(fmaxf(fabsf(a.x), fabsf(a.y)), fmaxf(fabsf(a.z), fabsf(a.w)));
}

// Handles the cold special row s==idx for one element (exec-mask skipped
// for all but 64 of 196608 rows).
__device__ __forceinline__ void special_fix(vf4& x, int i, int row, int idx,
                                            const vf4* __restrict__ new4,
                                            float inv) {
    if (__builtin_expect((row >> 6) == idx, 0)) {
        const int h = (row >> 2) & 15;
        const int b = row & 3;
        const vf4 n = new4[(b * NH + h) * (ND / 4) + (i & 31)];
        float m = max4abs(n);
        #pragma unroll
        for (int o = 16; o; o >>= 1)              // stays within 32-lane group
            m = fmaxf(m, __shfl_xor(m, o));
        const float q = 127.5f / m, d = m * inv;
        x.x = rintf(n.x * q) * d; x.y = rintf(n.y * q) * d;
        x.z = rintf(n.z * q) * d; x.w = rintf(n.w * q) * d;
    }
}

// K/V-split streaming dequant, 16 B/lane contiguous, exactly-resident grid
// (2048 blocks x 4 waves = 8192 waves = chip capacity, no tail), with a
// manual 2-deep load pipeline: both NT loads of an iteration pair issue
// before either dependent multiply/store, doubling in-flight loads/thread.
__global__ void __launch_bounds__(TPB, 8) kv_dequant_split(
    const vf4* __restrict__ key4, const vf4* __restrict__ val4,
    const vf4* __restrict__ ck,   const vf4* __restrict__ cv,
    const float* __restrict__ ksc, const float* __restrict__ vsc,
    const int* __restrict__ idxp,
    vf4* __restrict__ ok, vf4* __restrict__ ov)
{
    const float inv = 1.0f / 127.5f;
    const int idx  = *idxp;                       // uniform scalar load
    const int half = blockIdx.x >> 10;            // 0 = K, 1 = V
    const int tid  = (blockIdx.x & (HALF_BLOCKS - 1)) * TPB + threadIdx.x;

    const vf4*   src  = half ? cv   : ck;
    const float* sc   = half ? vsc  : ksc;
    const vf4*   new4 = half ? val4 : key4;
    vf4*         dst  = half ? ov   : ok;

    #pragma unroll
    for (int p = 0; p < ITERS; p += 2) {
        const int i0 = tid + p * STRIDE;
        const int i1 = i0 + STRIDE;
        // issue both NT loads before any dependent use
        vf4 x0 = __builtin_nontemporal_load(&src[i0]);
        vf4 x1 = __builtin_nontemporal_load(&src[i1]);
        const int r0 = i0 >> 5, r1 = i1 >> 5;
        x0 *= sc[r0] * inv;
        x1 *= sc[r1] * inv;
        special_fix(x0, i0, r0, idx, new4, inv);
        special_fix(x1, i1, r1, idx, new4, inv);
        __builtin_nontemporal_store(x0, &dst[i0]);
        __builtin_nontemporal_store(x1, &dst[i1]);
    }
}

extern "C" void kernel_launch(void* const* d_in, const int* in_sizes, int n_in,
                              void* d_out, int out_size, void* d_ws, size_t ws_size,
                              hipStream_t stream) {
    const float* key   = (const float*)d_in[0];
    const float* value = (const float*)d_in[1];
    const float* ck    = (const float*)d_in[2];
    const float* cv    = (const float*)d_in[3];
    const float* ksc   = (const float*)d_in[4];
    const float* vsc   = (const float*)d_in[5];
    const int*   idxp  = (const int*)d_in[6];

    float* out_k = (float*)d_out;
    float* out_v = (float*)d_out + NTOT;

    kv_dequant_split<<<dim3(2 * HALF_BLOCKS), dim3(TPB), 0, stream>>>(
        (const vf4*)key, (const vf4*)value,
        (const vf4*)ck, (const vf4*)cv,
        ksc, vsc, idxp,
        (vf4*)out_k, (vf4*)out_v);
}

// Round 10
// 71.968 us; speedup vs baseline: 1.0435x; 1.0435x over previous
//
#include <hip/hip_runtime.h>

// Problem constants (match reference)
#define S_AR 3072
#define NH 16
#define NB 4
#define ND 128
#define NTOT (S_AR * NH * NB * ND)   // 25,165,824 elems per tensor
#define N4   (NTOT / 4)              // 6,291,456 float4 per tensor
#define TPB 256
#define HALF_BLOCKS 1024             // blocks per tensor (2048 total = 8/CU, all-resident)
#define STRIDE (HALF_BLOCKS * TPB)   // 262,144 threads per tensor (2^18)
#define ITERS (N4 / STRIDE)          // exactly 24, no remainder

// Native clang vector type — required by __builtin_nontemporal_{load,store}
typedef float vf4 __attribute__((ext_vector_type(4)));

__device__ __forceinline__ float max4abs(vf4 a) {
    return fmaxf(fmaxf(fabsf(a.x), fabsf(a.y)), fmaxf(fabsf(a.z), fabsf(a.w)));
}

// K/V-split streaming dequant, 16 B/lane contiguous, exactly-resident grid:
// 2048 blocks x 4 waves = 8192 waves = one full scheduling generation
// (no second-generation tail). Blocks [0,HALF_BLOCKS) stream K, rest V.
// Hot path branchy-cold (beats vf8-stride, scale-prefetch, branch-free
// select, and manual 2-deep pipelining — the compiler's schedule for this
// simple form wins). One (s,h,b) row = 32 float4 = one aligned 32-lane group,
// so the special row s==idx reduces abs-max via __shfl_xor within the group.
__global__ void __launch_bounds__(TPB, 8) kv_dequant_split(
    const vf4* __restrict__ key4, const vf4* __restrict__ val4,
    const vf4* __restrict__ ck,   const vf4* __restrict__ cv,
    const float* __restrict__ ksc, const float* __restrict__ vsc,
    const int* __restrict__ idxp,
    vf4* __restrict__ ok, vf4* __restrict__ ov)
{
    const float inv = 1.0f / 127.5f;
    const int idx  = *idxp;                       // uniform scalar load
    const int half = blockIdx.x >> 10;            // 0 = K, 1 = V
    const int tid  = (blockIdx.x & (HALF_BLOCKS - 1)) * TPB + threadIdx.x;

    const vf4*   src  = half ? cv   : ck;
    const float* sc   = half ? vsc  : ksc;
    const vf4*   new4 = half ? val4 : key4;
    vf4*         dst  = half ? ov   : ok;

    #pragma unroll
    for (int it = 0; it < ITERS; ++it) {
        const int i   = tid + it * STRIDE;
        const int row = i >> 5;                   // (s,h,b) flat row
        vf4 x = __builtin_nontemporal_load(&src[i]);
        x *= sc[row] * inv;
        if (__builtin_expect((row >> 6) == idx, 0)) {   // s == idx : new step
            const int h = (row >> 2) & 15;
            const int b = row & 3;
            const vf4 n = new4[(b * NH + h) * (ND / 4) + (i & 31)];
            float m = max4abs(n);
            #pragma unroll
            for (int o = 16; o; o >>= 1)          // stays within 32-lane group
                m = fmaxf(m, __shfl_xor(m, o));
            const float q = 127.5f / m, d = m * inv;
            x.x = rintf(n.x * q) * d; x.y = rintf(n.y * q) * d;
            x.z = rintf(n.z * q) * d; x.w = rintf(n.w * q) * d;
        }
        __builtin_nontemporal_store(x, &dst[i]);
    }
}

extern "C" void kernel_launch(void* const* d_in, const int* in_sizes, int n_in,
                              void* d_out, int out_size, void* d_ws, size_t ws_size,
                              hipStream_t stream) {
    const float* key   = (const float*)d_in[0];
    const float* value = (const float*)d_in[1];
    const float* ck    = (const float*)d_in[2];
    const float* cv    = (const float*)d_in[3];
    const float* ksc   = (const float*)d_in[4];
    const float* vsc   = (const float*)d_in[5];
    const int*   idxp  = (const int*)d_in[6];

    float* out_k = (float*)d_out;
    float* out_v = (float*)d_out + NTOT;

    kv_dequant_split<<<dim3(2 * HALF_BLOCKS), dim3(TPB), 0, stream>>>(
        (const vf4*)key, (const vf4*)value,
        (const vf4*)ck, (const vf4*)cv,
        ksc, vsc, idxp,
        (vf4*)out_k, (vf4*)out_v);
}